// Round 10
// baseline (181.902 us; speedup 1.0000x reference)
//
#include <hip/hip_runtime.h>
#include <hip/hip_bf16.h>
#include <cstdint>
#include <cstddef>

#define NG 32
#define NP 64
#define ND 512
#define HW 192
#define EPSV 1e-5f

typedef _Float16 half8 __attribute__((ext_vector_type(8)));
typedef float floatx4 __attribute__((ext_vector_type(4)));
typedef float floatx16 __attribute__((ext_vector_type(16)));

// ---- probe pre-pass: prob[p][d][hw] f32 -> probT2[p][s][r][j] fp16 (s=d>>3, j=d&7)
// Fragment-ready k-major layout: a 32x32x16 A-frag load is one dwordx4 per lane.
__global__ __launch_bounds__(192) void prep_probe(const float* __restrict__ prob,
                                                  _Float16* __restrict__ probT2) {
  const int p = blockIdx.x, s = blockIdx.y;  // 64 x 64
  const int r = threadIdx.x;                 // 0..191
  const float* src = prob + ((size_t)p * ND + s * 8) * HW + r;
  half8 h;
#pragma unroll
  for (int j = 0; j < 8; ++j) h[j] = (_Float16)src[(size_t)j * HW];
  *(half8*)(probT2 + (((size_t)p * 64 + s) * HW + r) * 8) = h;
}

// ---- gal pre-pass: gal[g][d][x] f32 -> galT2[g][kt][rb][slot][row][j] fp16,
// d = kt*64 + slot*8 + j, x = rb*32 + row.  BYTE-IDENTICAL to the LDS tile
// layout: staging is a linear contiguous copy and LDS reads are conflict-free.
__global__ __launch_bounds__(256) void prep_gal2(const float* __restrict__ gal,
                                                 _Float16* __restrict__ galT2) {
  __shared__ _Float16 lds[64 * 192];  // [d][x]
  const int g = blockIdx.x, kt = blockIdx.y;
  const int t = threadIdx.x;
  const int lane = t & 63, wid = t >> 6;
  const float* src = gal + ((size_t)g * ND + kt * 64) * HW;
#pragma unroll
  for (int dd = 0; dd < 16; ++dd) {
    const int d = dd * 4 + wid;
#pragma unroll
    for (int c = 0; c < 3; ++c) {
      const int x = c * 64 + lane;
      lds[d * 192 + x] = (_Float16)src[(size_t)d * HW + x];
    }
  }
  __syncthreads();
  _Float16* dst = galT2 + ((size_t)(g * 8 + kt)) * 12288;
  const int slot = t >> 5, row = t & 31;
#pragma unroll
  for (int rb = 0; rb < 6; ++rb) {
    half8 h;
#pragma unroll
    for (int j = 0; j < 8; ++j) h[j] = lds[(slot * 8 + j) * 192 + rb * 32 + row];
    *(half8*)(dst + rb * 2048 + slot * 256 + row * 8) = h;
  }
}

// ---- async 16B global -> LDS
__device__ __forceinline__ void g2l16(const void* g, void* l) {
  __builtin_amdgcn_global_load_lds(
      (const __attribute__((address_space(1))) void*)g,
      (__attribute__((address_space(3))) void*)l, 16, 0, 0);
}

// ---- main fused kernel: one WG (384 thr, 6 waves) per (g,p) pair ----
// Wave grid 2(row wr) x 3(col wc); wave tile 96x64 via 3x2 frags of
// mfma_f32_32x32x16_f16 -> acc 96 AGPR/wave, ~155 unified regs -> 3 waves/SIMD
// (12 waves/CU) for latency hiding (R9 was 2/SIMD and pipes serialized).
// B (gal) staged from byte-identical galT2 (linear copy) into conflict-free
// LDS [rb][slot][row32][16B], BK=64 double-buffered; A (probe) global->VGPR
// from fragment-ready probT2, register-double-buffered.
__global__ __launch_bounds__(384, 3) void qaconv_main(
    const _Float16* __restrict__ galT2, const _Float16* __restrict__ probT2,
    const float* __restrict__ bn_w, const float* __restrict__ bn_b,
    const float* __restrict__ bn_m, const float* __restrict__ bn_v,
    const float* __restrict__ fc_w, const float* __restrict__ fc_b,
    const float* __restrict__ lbn_w, const float* __restrict__ lbn_b,
    const float* __restrict__ lbn_m, const float* __restrict__ lbn_v,
    float* __restrict__ out) {
  __shared__ __align__(16) char bufB[2 * 24576];  // 48 KB
  __shared__ float colp[2][HW];
  __shared__ float rowpart[3][HW];
  __shared__ float wsum[6];

  const int bid = blockIdx.x;
  const int g = bid >> 6, p = bid & 63;

  const int t = threadIdx.x;
  const int lane = t & 63, wid = t >> 6;     // wid 0..5
  const int wr = wid & 1;                    // probe-row half (96 rows)
  const int wc = wid >> 1;                   // gal-col third (64 cols): 0..2
  const int l31 = lane & 31, hi = lane >> 5;
  const int arow0 = wr * 96 + l31;

  // A base: probT2 offset ((p*64 + s)*HW + r)*8, s = 2*idx + hi, idx 0..31
  const _Float16* aBase = probT2 + (((size_t)p * 64 + hi) * HW + arow0) * 8;

  // B staging: galT2 tile (g,kt) is byte-identical to the LDS buffer.
  // 384 threads x 16B = 6144B per round; 4 rounds cover 24576B.
  const _Float16* gB2 = galT2 + (size_t)g * 8 * 12288 + (size_t)t * 8;
  const int sdst = wid * 1024;  // wave-uniform LDS dest base (+ lane*16 by HW)

  floatx16 acc[3][2];
#pragma unroll
  for (int ii = 0; ii < 3; ++ii)
#pragma unroll
    for (int jj = 0; jj < 2; ++jj) acc[ii][jj] = (floatx16)0.f;

#define STAGE_B(kt_, buf_)                                          \
  {                                                                 \
    char* db_ = bufB + (buf_)*24576 + sdst;                         \
    const _Float16* sb_ = gB2 + (size_t)(kt_)*12288;                \
    _Pragma("unroll") for (int r_ = 0; r_ < 4; ++r_)                \
        g2l16(sb_ + (size_t)r_ * 3072, db_ + r_ * 6144);            \
  }

#define LOAD_AF(dst, idx_)                                          \
  {                                                                 \
    const _Float16* ap_ = aBase + (size_t)(idx_) * (2 * HW * 8);    \
    dst[0] = *(const half8*)(ap_);                                  \
    dst[1] = *(const half8*)(ap_ + 32 * 8);                         \
    dst[2] = *(const half8*)(ap_ + 64 * 8);                         \
  }

#define KC_BODY(kc_, AFU, AFL, nidx_)                                            \
  {                                                                              \
    LOAD_AF(AFL, nidx_);                                                         \
    half8 bf[2];                                                                 \
    const int boff_ = ((kc_)*2 + hi) * 512 + l31 * 16;                           \
    bf[0] = *(const half8*)(bcur + (wc * 2 + 0) * 4096 + boff_);                 \
    bf[1] = *(const half8*)(bcur + (wc * 2 + 1) * 4096 + boff_);                 \
    __builtin_amdgcn_s_setprio(1);                                               \
    _Pragma("unroll") for (int ii = 0; ii < 3; ++ii)                             \
        _Pragma("unroll") for (int jj = 0; jj < 2; ++jj)                         \
            acc[ii][jj] = __builtin_amdgcn_mfma_f32_32x32x16_f16(AFU[ii], bf[jj],\
                                                                 acc[ii][jj], 0, 0, 0); \
    __builtin_amdgcn_s_setprio(0);                                               \
  }

  half8 af0[3], af1[3];
  STAGE_B(0, 0);
  LOAD_AF(af0, 0);
  __syncthreads();  // prologue: full drain, B(0) staged by all waves

  for (int kt = 0; kt < 8; ++kt) {
    if (kt < 7) STAGE_B(kt + 1, (kt & 1) ^ 1);
    const char* bcur = bufB + (kt & 1) * 24576;
    const int i0 = kt * 4;
    const int n4 = (kt < 7) ? i0 + 4 : 31;  // clamp last prefetch (in-bounds dummy)
    KC_BODY(0, af0, af1, i0 + 1)
    KC_BODY(1, af1, af0, i0 + 2)
    KC_BODY(2, af0, af1, i0 + 3)
    KC_BODY(3, af1, af0, n4)
    __syncthreads();  // stage(kt+1) drained; all waves done reading bufB[kt&1]
  }

  // ---- epilogue: dual-axis max ----
  // C/D map: col X = wc*64 + fb*32 + l31, row Y = wr*96 + fa*32 + (e&3)+8*(e>>2)+4*hi
#pragma unroll
  for (int fb = 0; fb < 2; ++fb) {
    float v = -3.4e38f;
#pragma unroll
    for (int fa = 0; fa < 3; ++fa)
#pragma unroll
      for (int e = 0; e < 16; ++e) v = fmaxf(v, acc[fa][fb][e]);
    v = fmaxf(v, __shfl_xor(v, 32));
    if (lane < 32) colp[wr][wc * 64 + fb * 32 + lane] = v;
  }
  // rowmax: lane-local over 2 col-frags, then 5-step butterfly across l31
#pragma unroll
  for (int fa = 0; fa < 3; ++fa)
#pragma unroll
    for (int e = 0; e < 16; ++e) {
      float rv = fmaxf(acc[fa][0][e], acc[fa][1][e]);
      rv = fmaxf(rv, __shfl_xor(rv, 1));
      rv = fmaxf(rv, __shfl_xor(rv, 2));
      rv = fmaxf(rv, __shfl_xor(rv, 4));
      rv = fmaxf(rv, __shfl_xor(rv, 8));
      rv = fmaxf(rv, __shfl_xor(rv, 16));
      if (l31 == 0) {
        const int Y = wr * 96 + fa * 32 + (e & 3) + 8 * (e >> 2) + 4 * hi;
        rowpart[wc][Y] = rv;
      }
    }
  __syncthreads();

  // ---- fused BN -> fc dot -> logit BN -> sigmoid ----
  float partial = 0.f;
  if (t < HW) {
    const float rmax =
        fmaxf(fmaxf(rowpart[0][t], rowpart[1][t]), rowpart[2][t]);
    const float cmax = fmaxf(colp[0][t], colp[1][t]);
    const float scale = bn_w[0] / sqrtf(bn_v[0] + EPSV);
    const float bm = bn_m[0], bb = bn_b[0];
    partial = ((cmax - bm) * scale + bb) * fc_w[t] +
              ((rmax - bm) * scale + bb) * fc_w[HW + t];
  }
#pragma unroll
  for (int off = 1; off < 64; off <<= 1) partial += __shfl_xor(partial, off);
  if (lane == 0) wsum[wid] = partial;
  __syncthreads();
  if (t == 0) {
    float sum = fc_b[0];
#pragma unroll
    for (int w = 0; w < 6; ++w) sum += wsum[w];
    const float logit = (sum - lbn_m[0]) * (lbn_w[0] / sqrtf(lbn_v[0] + EPSV)) + lbn_b[0];
    out[bid] = 1.f / (1.f + expf(-logit * 0.1f));
  }
#undef STAGE_B
#undef LOAD_AF
#undef KC_BODY
}

// ---------------- naive f32 fallback (only if ws too small) ----------------
__global__ __launch_bounds__(256) void qaconv_naive(
    const float* __restrict__ gal, const float* __restrict__ prob,
    const float* __restrict__ bn_w, const float* __restrict__ bn_b,
    const float* __restrict__ bn_m, const float* __restrict__ bn_v,
    const float* __restrict__ fc_w, const float* __restrict__ fc_b,
    const float* __restrict__ lbn_w, const float* __restrict__ lbn_b,
    const float* __restrict__ lbn_m, const float* __restrict__ lbn_v,
    float* __restrict__ out) {
  __shared__ float prow[ND];
  __shared__ float rowmaxs[HW];
  __shared__ float colmaxs[HW];
  __shared__ float red[4];
  const int bid = blockIdx.x;
  const int g = bid >> 6, p = bid & 63;
  const int t = threadIdx.x, lane = t & 63, wid = t >> 6;
  const float* gp = gal + (size_t)g * ND * HW;
  const float* pp = prob + (size_t)p * ND * HW;
  float colmax = -3.4e38f;
  for (int y = 0; y < HW; ++y) {
    for (int k = t; k < ND; k += 256) prow[k] = pp[(size_t)k * HW + y];
    __syncthreads();
    float sv = -3.4e38f;
    if (t < HW) {
      sv = 0.f;
      for (int k = 0; k < ND; ++k) sv = fmaf(prow[k], gp[(size_t)k * HW + t], sv);
      colmax = fmaxf(colmax, sv);
    }
    float m = sv;
#pragma unroll
    for (int off = 1; off < 64; off <<= 1) m = fmaxf(m, __shfl_xor(m, off));
    if (lane == 0) red[wid] = m;
    __syncthreads();
    if (t == 0) rowmaxs[y] = fmaxf(fmaxf(red[0], red[1]), fmaxf(red[2], red[3]));
    __syncthreads();
  }
  if (t < HW) colmaxs[t] = colmax;
  __syncthreads();
  float partial = 0.f;
  for (int j = t; j < 2 * HW; j += 256) {
    const float v = (j < HW) ? colmaxs[j] : rowmaxs[j - HW];
    const float sc = (v - bn_m[0]) * (bn_w[0] / sqrtf(bn_v[0] + EPSV)) + bn_b[0];
    partial += sc * fc_w[j];
  }
#pragma unroll
  for (int off = 1; off < 64; off <<= 1) partial += __shfl_xor(partial, off);
  if (lane == 0) red[wid] = partial;
  __syncthreads();
  if (t == 0) {
    const float sum = fc_b[0] + red[0] + red[1] + red[2] + red[3];
    const float logit = (sum - lbn_m[0]) * (lbn_w[0] / sqrtf(lbn_v[0] + EPSV)) + lbn_b[0];
    out[bid] = 1.f / (1.f + expf(-logit * 0.1f));
  }
}

extern "C" void kernel_launch(void* const* d_in, const int* in_sizes, int n_in,
                              void* d_out, int out_size, void* d_ws, size_t ws_size,
                              hipStream_t stream) {
  const float* gal = (const float*)d_in[0];
  const float* prob = (const float*)d_in[1];
  const float* bn_w = (const float*)d_in[2];
  const float* bn_b = (const float*)d_in[3];
  const float* bn_m = (const float*)d_in[4];
  const float* bn_v = (const float*)d_in[5];
  const float* fc_w = (const float*)d_in[6];
  const float* fc_b = (const float*)d_in[7];
  const float* lbn_w = (const float*)d_in[8];
  const float* lbn_b = (const float*)d_in[9];
  const float* lbn_m = (const float*)d_in[10];
  const float* lbn_v = (const float*)d_in[11];
  float* out = (float*)d_out;

  const size_t probT2_elems = (size_t)NP * 64 * HW * 8;  // 6.29M halves
  const size_t galT2_elems = (size_t)NG * 8 * 12288;     // 3.15M halves
  const size_t ws_needed = (probT2_elems + galT2_elems) * sizeof(_Float16);
  if (ws_size >= ws_needed) {
    _Float16* probT2 = (_Float16*)d_ws;
    _Float16* galT2 = probT2 + probT2_elems;
    prep_probe<<<dim3(NP, 64), dim3(192), 0, stream>>>(prob, probT2);
    prep_gal2<<<dim3(NG, 8), dim3(256), 0, stream>>>(gal, galT2);
    qaconv_main<<<dim3(NG * NP), dim3(384), 0, stream>>>(
        galT2, probT2, bn_w, bn_b, bn_m, bn_v, fc_w, fc_b, lbn_w, lbn_b, lbn_m, lbn_v, out);
  } else {
    qaconv_naive<<<dim3(NG * NP), dim3(256), 0, stream>>>(
        gal, prob, bn_w, bn_b, bn_m, bn_v, fc_w, fc_b, lbn_w, lbn_b, lbn_m, lbn_v, out);
  }
}

// Round 11
// 91.381 us; speedup vs baseline: 1.9906x; 1.9906x over previous
//
#include <hip/hip_runtime.h>
#include <hip/hip_bf16.h>
#include <cstdint>
#include <cstddef>

#define NG 32
#define NP 64
#define ND 512
#define HW 192
#define KT2 16  // number of BK=32 K-tiles
#define EPSV 1e-5f

typedef _Float16 half8 __attribute__((ext_vector_type(8)));
typedef float floatx4 __attribute__((ext_vector_type(4)));
typedef float floatx16 __attribute__((ext_vector_type(16)));

// ---- unified pre-pass: src[b][d][x] f32 -> tiles[b][kt2][h]*8 fp16, BK=32.
// h = rb*128 + kc*64 + hi*32 + l31 ; element j = src[kt2*32 + kc*16 + hi*8 + j][rb*32 + l31].
// This is BYTE-IDENTICAL to the LDS tile layout consumed by the main kernel, so
// staging is a pure linear copy and all LDS reads are conflict-free.  The SAME
// transform serves both operands (A row=probe-y, B row=gal-x).
__global__ __launch_bounds__(256) void prep_tiles(const float* __restrict__ gal,
                                                  const float* __restrict__ prob,
                                                  _Float16* __restrict__ galT3,
                                                  _Float16* __restrict__ probT3) {
  const int z = blockIdx.x;    // 0..95: first NP=probe, then NG=gal
  const int kt2 = blockIdx.y;  // 0..15
  const float* src;
  _Float16* dst;
  if (z < NP) {
    src = prob + (size_t)z * ND * HW;
    dst = probT3 + (size_t)z * KT2 * 6144;
  } else {
    src = gal + (size_t)(z - NP) * ND * HW;
    dst = galT3 + (size_t)(z - NP) * KT2 * 6144;
  }
  src += (size_t)kt2 * 32 * HW;
  dst += (size_t)kt2 * 6144;
  const int t = threadIdx.x;
#pragma unroll
  for (int r = 0; r < 3; ++r) {
    const int h = r * 256 + t;
    const int rb = h >> 7, kc = (h >> 6) & 1, hi = (h >> 5) & 1, l31 = h & 31;
    const float* sp = src + (size_t)(kc * 16 + hi * 8) * HW + rb * 32 + l31;
    half8 v;
#pragma unroll
    for (int j = 0; j < 8; ++j) v[j] = (_Float16)sp[(size_t)j * HW];
    *(half8*)(dst + (size_t)h * 8) = v;
  }
}

// ---- async 16B global -> LDS
__device__ __forceinline__ void g2l16(const void* g, void* l) {
  __builtin_amdgcn_global_load_lds(
      (const __attribute__((address_space(1))) void*)g,
      (__attribute__((address_space(3))) void*)l, 16, 0, 0);
}

// ---- main fused kernel: one WG (256 thr, 4 waves) per (g,p) pair ----
// 4 waves in 2(wr) x 2(wc); each computes 96x96 via 3x3 frags of
// mfma_f32_32x32x16_f16.  BOTH operands staged in LDS (BK=32, A+B double-
// buffered = 48KB) from byte-identical pre-tiled probT3/galT3: staging is a
// linear global_load_lds copy, reads are conflict-free, and the per-kc operand
// dependency is ds_read (~120cy) instead of global (~300cy) -- hidden by the
// compiler's lgkmcnt pipelining plus the antiphase partner block.
__global__ __launch_bounds__(256, 2) void qaconv_main(
    const _Float16* __restrict__ galT3, const _Float16* __restrict__ probT3,
    const float* __restrict__ bn_w, const float* __restrict__ bn_b,
    const float* __restrict__ bn_m, const float* __restrict__ bn_v,
    const float* __restrict__ fc_w, const float* __restrict__ fc_b,
    const float* __restrict__ lbn_w, const float* __restrict__ lbn_b,
    const float* __restrict__ lbn_m, const float* __restrict__ lbn_v,
    float* __restrict__ out) {
  // union: K-loop buf[2][A 12288 | B 12288] (49152 B); epilogue rowbuf[192][66] f32
  __shared__ __align__(16) char shmem[50688];
  __shared__ float colp[2][HW];
  __shared__ float wsum[4];
  char* bufs = shmem;
  float(*rowbuf)[66] = (float(*)[66])shmem;

  const int bid = blockIdx.x;
  const int g = bid >> 6, p = bid & 63;

  const int t = threadIdx.x;
  const int lane = t & 63, wid = t >> 6;
  const int wr = wid & 1;   // probe-row half (y block of 96)
  const int wc = wid >> 1;  // gal-col half (x block of 96)
  const int l31 = lane & 31, hi = lane >> 5;

  // staging sources (per-lane): lane reads 16B at base + lane*16, wave-chunk 1KB
  const _Float16* pAl = probT3 + (size_t)p * KT2 * 6144 + wid * 512 + lane * 8;
  const _Float16* pBl = galT3 + (size_t)g * KT2 * 6144 + wid * 512 + lane * 8;
  const int sdst = wid * 1024;  // wave-uniform LDS dest base (+ lane*16 by HW)

  floatx16 acc[3][3];
#pragma unroll
  for (int ii = 0; ii < 3; ++ii)
#pragma unroll
    for (int jj = 0; jj < 3; ++jj) acc[ii][jj] = (floatx16)0.f;

#define STAGE(kt_, b_)                                               \
  {                                                                  \
    char* db_ = bufs + (b_)*24576 + sdst;                            \
    const _Float16* sa_ = pAl + (size_t)(kt_)*6144;                  \
    const _Float16* sb_ = pBl + (size_t)(kt_)*6144;                  \
    _Pragma("unroll") for (int r_ = 0; r_ < 3; ++r_)                 \
        g2l16(sa_ + (size_t)r_ * 2048, db_ + r_ * 4096);             \
    _Pragma("unroll") for (int r_ = 0; r_ < 3; ++r_)                 \
        g2l16(sb_ + (size_t)r_ * 2048, db_ + 12288 + r_ * 4096);     \
  }

#define KC_BODY(kc_)                                                             \
  {                                                                              \
    half8 af[3], bf[3];                                                          \
    const int off_ = (kc_)*1024 + hi * 512 + l31 * 16;                           \
    af[0] = *(const half8*)(bA + (wr * 3 + 0) * 2048 + off_);                    \
    af[1] = *(const half8*)(bA + (wr * 3 + 1) * 2048 + off_);                    \
    af[2] = *(const half8*)(bA + (wr * 3 + 2) * 2048 + off_);                    \
    bf[0] = *(const half8*)(bB + (wc * 3 + 0) * 2048 + off_);                    \
    bf[1] = *(const half8*)(bB + (wc * 3 + 1) * 2048 + off_);                    \
    bf[2] = *(const half8*)(bB + (wc * 3 + 2) * 2048 + off_);                    \
    __builtin_amdgcn_s_setprio(1);                                               \
    _Pragma("unroll") for (int ii = 0; ii < 3; ++ii)                             \
        _Pragma("unroll") for (int jj = 0; jj < 3; ++jj)                         \
            acc[ii][jj] = __builtin_amdgcn_mfma_f32_32x32x16_f16(af[ii], bf[jj], \
                                                                 acc[ii][jj], 0, 0, 0); \
    __builtin_amdgcn_s_setprio(0);                                               \
  }

  STAGE(0, 0);
  __syncthreads();  // prologue: tile 0 staged by all waves

  for (int kt = 0; kt < KT2; ++kt) {
    if (kt < KT2 - 1) STAGE(kt + 1, (kt & 1) ^ 1);
    const char* bA = bufs + (kt & 1) * 24576;
    const char* bB = bA + 12288;
    KC_BODY(0)
    KC_BODY(1)
    __syncthreads();  // stage(kt+1) drained; all waves done reading buf[kt&1]
  }

  // ---- epilogue: dual-axis max ----
  // C/D map: col X = wc*96 + fb*32 + l31, row Y = wr*96 + fa*32 + (e&3)+8*(e>>2)+4*hi
#pragma unroll
  for (int fb = 0; fb < 3; ++fb) {
    float v = -3.4e38f;
#pragma unroll
    for (int fa = 0; fa < 3; ++fa)
#pragma unroll
      for (int e = 0; e < 16; ++e) v = fmaxf(v, acc[fa][fb][e]);
    v = fmaxf(v, __shfl_xor(v, 32));
    if (lane < 32) colp[wr][wc * 96 + fb * 32 + lane] = v;
  }
  // rowmax partials -> rowbuf (overlays bufs; safe after the loop's final barrier)
#pragma unroll
  for (int fa = 0; fa < 3; ++fa)
#pragma unroll
    for (int e = 0; e < 16; ++e) {
      float rv = acc[fa][0][e];
      rv = fmaxf(rv, acc[fa][1][e]);
      rv = fmaxf(rv, acc[fa][2][e]);
      const int Y = wr * 96 + fa * 32 + (e & 3) + 8 * (e >> 2) + 4 * hi;
      rowbuf[Y][wc * 32 + l31] = rv;
    }
  __syncthreads();

  // ---- fused BN -> fc dot -> logit BN -> sigmoid ----
  float partial = 0.f;
  if (t < HW) {
    const float* rb = rowbuf[t];
    float rmax = -3.4e38f;
#pragma unroll
    for (int j = 0; j < 16; ++j) {
      const floatx4 v = *(const floatx4*)&rb[j * 4];
      rmax = fmaxf(rmax, fmaxf(fmaxf(v[0], v[1]), fmaxf(v[2], v[3])));
    }
    const float cmax = fmaxf(colp[0][t], colp[1][t]);
    const float scale = bn_w[0] / sqrtf(bn_v[0] + EPSV);
    const float bm = bn_m[0], bb = bn_b[0];
    partial = ((cmax - bm) * scale + bb) * fc_w[t] +
              ((rmax - bm) * scale + bb) * fc_w[HW + t];
  }
#pragma unroll
  for (int off = 1; off < 64; off <<= 1) partial += __shfl_xor(partial, off);
  if (lane == 0) wsum[wid] = partial;
  __syncthreads();
  if (t == 0) {
    const float sum = fc_b[0] + wsum[0] + wsum[1] + wsum[2] + wsum[3];
    const float logit = (sum - lbn_m[0]) * (lbn_w[0] / sqrtf(lbn_v[0] + EPSV)) + lbn_b[0];
    out[bid] = 1.f / (1.f + expf(-logit * 0.1f));
  }
#undef STAGE
#undef KC_BODY
}

// ---------------- naive f32 fallback (only if ws too small) ----------------
__global__ __launch_bounds__(256) void qaconv_naive(
    const float* __restrict__ gal, const float* __restrict__ prob,
    const float* __restrict__ bn_w, const float* __restrict__ bn_b,
    const float* __restrict__ bn_m, const float* __restrict__ bn_v,
    const float* __restrict__ fc_w, const float* __restrict__ fc_b,
    const float* __restrict__ lbn_w, const float* __restrict__ lbn_b,
    const float* __restrict__ lbn_m, const float* __restrict__ lbn_v,
    float* __restrict__ out) {
  __shared__ float prow[ND];
  __shared__ float rowmaxs[HW];
  __shared__ float colmaxs[HW];
  __shared__ float red[4];
  const int bid = blockIdx.x;
  const int g = bid >> 6, p = bid & 63;
  const int t = threadIdx.x, lane = t & 63, wid = t >> 6;
  const float* gp = gal + (size_t)g * ND * HW;
  const float* pp = prob + (size_t)p * ND * HW;
  float colmax = -3.4e38f;
  for (int y = 0; y < HW; ++y) {
    for (int k = t; k < ND; k += 256) prow[k] = pp[(size_t)k * HW + y];
    __syncthreads();
    float sv = -3.4e38f;
    if (t < HW) {
      sv = 0.f;
      for (int k = 0; k < ND; ++k) sv = fmaf(prow[k], gp[(size_t)k * HW + t], sv);
      colmax = fmaxf(colmax, sv);
    }
    float m = sv;
#pragma unroll
    for (int off = 1; off < 64; off <<= 1) m = fmaxf(m, __shfl_xor(m, off));
    if (lane == 0) red[wid] = m;
    __syncthreads();
    if (t == 0) rowmaxs[y] = fmaxf(fmaxf(red[0], red[1]), fmaxf(red[2], red[3]));
    __syncthreads();
  }
  if (t < HW) colmaxs[t] = colmax;
  __syncthreads();
  float partial = 0.f;
  for (int j = t; j < 2 * HW; j += 256) {
    const float v = (j < HW) ? colmaxs[j] : rowmaxs[j - HW];
    const float sc = (v - bn_m[0]) * (bn_w[0] / sqrtf(bn_v[0] + EPSV)) + bn_b[0];
    partial += sc * fc_w[j];
  }
#pragma unroll
  for (int off = 1; off < 64; off <<= 1) partial += __shfl_xor(partial, off);
  if (lane == 0) red[wid] = partial;
  __syncthreads();
  if (t == 0) {
    const float sum = fc_b[0] + red[0] + red[1] + red[2] + red[3];
    const float logit = (sum - lbn_m[0]) * (lbn_w[0] / sqrtf(lbn_v[0] + EPSV)) + lbn_b[0];
    out[bid] = 1.f / (1.f + expf(-logit * 0.1f));
  }
}

extern "C" void kernel_launch(void* const* d_in, const int* in_sizes, int n_in,
                              void* d_out, int out_size, void* d_ws, size_t ws_size,
                              hipStream_t stream) {
  const float* gal = (const float*)d_in[0];
  const float* prob = (const float*)d_in[1];
  const float* bn_w = (const float*)d_in[2];
  const float* bn_b = (const float*)d_in[3];
  const float* bn_m = (const float*)d_in[4];
  const float* bn_v = (const float*)d_in[5];
  const float* fc_w = (const float*)d_in[6];
  const float* fc_b = (const float*)d_in[7];
  const float* lbn_w = (const float*)d_in[8];
  const float* lbn_b = (const float*)d_in[9];
  const float* lbn_m = (const float*)d_in[10];
  const float* lbn_v = (const float*)d_in[11];
  float* out = (float*)d_out;

  const size_t probT3_elems = (size_t)NP * KT2 * 6144;  // 6.29M halves
  const size_t galT3_elems = (size_t)NG * KT2 * 6144;   // 3.15M halves
  const size_t ws_needed = (probT3_elems + galT3_elems) * sizeof(_Float16);
  if (ws_size >= ws_needed) {
    _Float16* probT3 = (_Float16*)d_ws;
    _Float16* galT3 = probT3 + probT3_elems;
    prep_tiles<<<dim3(NP + NG, KT2), dim3(256), 0, stream>>>(gal, prob, galT3, probT3);
    qaconv_main<<<dim3(NG * NP), dim3(256), 0, stream>>>(
        galT3, probT3, bn_w, bn_b, bn_m, bn_v, fc_w, fc_b, lbn_w, lbn_b, lbn_m, lbn_v, out);
  } else {
    qaconv_naive<<<dim3(NG * NP), dim3(256), 0, stream>>>(
        gal, prob, bn_w, bn_b, bn_m, bn_v, fc_w, fc_b, lbn_w, lbn_b, lbn_m, lbn_v, out);
  }
}